// Round 2
// baseline (9305.537 us; speedup 1.0000x reference)
//
#include <hip/hip_runtime.h>
#include <stdint.h>

// LocalAttentionBlock: B=4 S=16384 K=16 C=64 MID=16. N = B*S = 65536 points.
// Inputs/outputs are fp32 (values bf16-grid-quantized by harness).
// Round 2: correctness baseline, fp32 I/O. One wave per block, lane = channel o.
// Weights packed to bf16 pairs in VGPRs (exact for grid values); fp32 FMA.

#define KNB 16
#define PPB 8   // points per block

__device__ __forceinline__ float blo(uint32_t u){ return __uint_as_float(u << 16); }
__device__ __forceinline__ float bhi(uint32_t u){ return __uint_as_float(u & 0xffff0000u); }
__device__ __forceinline__ uint32_t pack2(float a, float b){
  uint32_t ua = __float_as_uint(a), ub = __float_as_uint(b);
  uint32_t ra = (ua + 0x7fffu + ((ua >> 16) & 1u)) >> 16;   // RNE fp32->bf16
  uint32_t rb = (ub + 0x7fffu + ((ub >> 16) & 1u)) >> 16;
  return (rb << 16) | ra;
}

__global__ __launch_bounds__(64) void pt_attn(
    const float* __restrict__ cxyz,   // (N,3)
    const float* __restrict__ cfeat,  // (N,64)
    const float* __restrict__ nxyz,   // (N,16,3)
    const float* __restrict__ nfeat,  // (N,16,64)
    const float* __restrict__ Wq,     // (64,64) (o,c)
    const float* __restrict__ Wk,
    const float* __restrict__ Wv,
    const float* __restrict__ Wpe1,   // (64,3)
    const float* __restrict__ Wpe2,   // (64,64)
    const float* __restrict__ Wa1,    // (16,64)
    const float* __restrict__ Wa2,    // (64,16)
    const float* __restrict__ Wproj,  // (64,64)
    const float* __restrict__ lnw,    // (64)
    const float* __restrict__ lnb,    // (64)
    float* __restrict__ out,          // (N,64)
    int npts)
{
  const int o = threadIdx.x;   // 0..63 == output channel

  __shared__ float scf[64];       // center feature
  __shared__ float srow[4][64];   // 4 staged neighbor-feature rows
  __shared__ float sbuf[64];      // t / x / attn scratch
  __shared__ float sh[16];        // a-MLP hidden

  // ---- cache weight rows as packed bf16 pairs (once per block) ----
  uint32_t wq[32], wk[32], wv[32], wp2[32], wa1r[32], wpj[32], wa2r[8];
  {
    const float2* Wq2  = (const float2*)Wq;
    const float2* Wk2  = (const float2*)Wk;
    const float2* Wv2  = (const float2*)Wv;
    const float2* Wp22 = (const float2*)Wpe2;
    const float2* Wa12 = (const float2*)Wa1;
    const float2* Wpj2 = (const float2*)Wproj;
    const float2* Wa22 = (const float2*)Wa2;
#pragma unroll
    for (int j = 0; j < 32; j++) {
      float2 a;
      a = Wq2 [o * 32 + j];        wq[j]   = pack2(a.x, a.y);
      a = Wk2 [o * 32 + j];        wk[j]   = pack2(a.x, a.y);
      a = Wv2 [o * 32 + j];        wv[j]   = pack2(a.x, a.y);
      a = Wp22[o * 32 + j];        wp2[j]  = pack2(a.x, a.y);
      a = Wa12[(o & 15) * 32 + j]; wa1r[j] = pack2(a.x, a.y);  // lane o -> h[m=o&15]
      a = Wpj2[o * 32 + j];        wpj[j]  = pack2(a.x, a.y);
    }
#pragma unroll
    for (int j = 0; j < 8; j++) { float2 a = Wa22[o * 8 + j]; wa2r[j] = pack2(a.x, a.y); }
  }
  const float p10 = Wpe1[o * 3 + 0];
  const float p11 = Wpe1[o * 3 + 1];
  const float p12 = Wpe1[o * 3 + 2];
  const float lnw_o = lnw[o], lnb_o = lnb[o];

  for (int p = 0; p < PPB; p++) {
    const int n = blockIdx.x * PPB + p;
    if (n >= npts) break;

    const float cf_o = cfeat[(size_t)n * 64 + o];
    __syncthreads();
    scf[o] = cf_o;
    __syncthreads();

    // q_o = sum_c Wq[o,c] * cf[c]
    float q_o = 0.f;
#pragma unroll
    for (int j = 0; j < 32; j++) {
      q_o += blo(wq[j]) * scf[2 * j];
      q_o += bhi(wq[j]) * scf[2 * j + 1];
    }

    const float cx0 = cxyz[n * 3 + 0];
    const float cx1 = cxyz[n * 3 + 1];
    const float cx2 = cxyz[n * 3 + 2];

    // online softmax state
    float m_run = -1e30f, l_run = 0.f, acc = 0.f;

    for (int kc = 0; kc < 4; kc++) {
      // stage 4 neighbor rows: lane o loads float4 (16B coalesced)
      __syncthreads();
      const float4 f4 = *(const float4*)(nfeat + (size_t)n * (KNB * 64) + kc * 256 + o * 4);
      *(float4*)&srow[o >> 4][(o & 15) * 4] = f4;
      __syncthreads();

#pragma unroll
      for (int ki = 0; ki < 4; ki++) {
        const int k = kc * 4 + ki;
        const float* nf = srow[ki];

        float kk = 0.f, vv = 0.f;
#pragma unroll
        for (int j = 0; j < 32; j++) {
          const float xlo = nf[2 * j], xhi = nf[2 * j + 1];
          kk += blo(wk[j]) * xlo; kk += bhi(wk[j]) * xhi;
          vv += blo(wv[j]) * xlo; vv += bhi(wv[j]) * xhi;
        }

        // rel-pos MLP layer 1
        const float rx = nxyz[(n * KNB + k) * 3 + 0] - cx0;
        const float ry = nxyz[(n * KNB + k) * 3 + 1] - cx1;
        const float rz = nxyz[(n * KNB + k) * 3 + 2] - cx2;
        const float t_o = fmaxf(p10 * rx + p11 * ry + p12 * rz, 0.f);

        __syncthreads();
        sbuf[o] = t_o;
        __syncthreads();

        float pe = 0.f;
#pragma unroll
        for (int j = 0; j < 32; j++) {
          pe += blo(wp2[j]) * sbuf[2 * j];
          pe += bhi(wp2[j]) * sbuf[2 * j + 1];
        }

        const float x_o = q_o - kk + pe;

        __syncthreads();
        sbuf[o] = x_o;
        __syncthreads();

        // h[m] = relu(Wa1[m,:] . x), lane o computes m = o&15 (4x redundant)
        float hm = 0.f;
#pragma unroll
        for (int j = 0; j < 32; j++) {
          hm += blo(wa1r[j]) * sbuf[2 * j];
          hm += bhi(wa1r[j]) * sbuf[2 * j + 1];
        }
        hm = fmaxf(hm, 0.f);
        if (o < 16) sh[o] = hm;
        __syncthreads();

        // w_o = Wa2[o,:] . h
        float wo = 0.f;
#pragma unroll
        for (int j = 0; j < 8; j++) {
          wo += blo(wa2r[j]) * sh[2 * j];
          wo += bhi(wa2r[j]) * sh[2 * j + 1];
        }

        // online softmax update
        const float m_new = fmaxf(m_run, wo);
        const float alpha = __expf(m_run - m_new);
        const float e     = __expf(wo - m_new);
        l_run = l_run * alpha + e;
        acc   = acc * alpha + e * (vv + pe);
        m_run = m_new;
      }
    }

    const float attn = acc / l_run;

    __syncthreads();
    sbuf[o] = attn;
    __syncthreads();

    float pr = 0.f;
#pragma unroll
    for (int j = 0; j < 32; j++) {
      pr += blo(wpj[j]) * sbuf[2 * j];
      pr += bhi(wpj[j]) * sbuf[2 * j + 1];
    }
    const float res = pr + cf_o;   // residual (identity)

    // layernorm across 64 lanes
    float s = res;
#pragma unroll
    for (int off = 32; off >= 1; off >>= 1) s += __shfl_xor(s, off, 64);
    const float mu = s * (1.f / 64.f);
    const float d = res - mu;
    float vs = d * d;
#pragma unroll
    for (int off = 32; off >= 1; off >>= 1) vs += __shfl_xor(vs, off, 64);
    const float var = vs * (1.f / 64.f);
    const float y = d * rsqrtf(var + 1e-5f) * lnw_o + lnb_o;

    out[(size_t)n * 64 + o] = y;
  }
}

extern "C" void kernel_launch(void* const* d_in, const int* in_sizes, int n_in,
                              void* d_out, int out_size, void* d_ws, size_t ws_size,
                              hipStream_t stream) {
  const float* cxyz  = (const float*)d_in[0];
  const float* cfeat = (const float*)d_in[1];
  const float* nxyz  = (const float*)d_in[2];
  const float* nfeat = (const float*)d_in[3];
  const float* Wq    = (const float*)d_in[4];
  const float* Wk    = (const float*)d_in[5];
  const float* Wv    = (const float*)d_in[6];
  const float* Wpe1  = (const float*)d_in[7];
  const float* Wpe2  = (const float*)d_in[8];
  const float* Wa1   = (const float*)d_in[9];
  const float* Wa2   = (const float*)d_in[10];
  const float* Wproj = (const float*)d_in[11];
  const float* lnw   = (const float*)d_in[12];
  const float* lnb   = (const float*)d_in[13];

  const int npts = in_sizes[1] / 64;   // B*S from center_feat
  const int nblk = (npts + PPB - 1) / PPB;
  pt_attn<<<nblk, 64, 0, stream>>>(cxyz, cfeat, nxyz, nfeat, Wq, Wk, Wv, Wpe1, Wpe2,
                                   Wa1, Wa2, Wproj, lnw, lnb, (float*)d_out, npts);
}

// Round 4
// 499.720 us; speedup vs baseline: 18.6215x; 18.6215x over previous
//
#include <hip/hip_runtime.h>
#include <stdint.h>

// LocalAttentionBlock (point-transformer), B=4 S=16384 K=16 C=64 MID=16, fp32 I/O
// (values bf16-grid). MFMA: 16 pts/block, wave=4 pts, point = 16x16 M-tile.
// Fused weights Wa1@Wk, Wa1@Wpe2, Wa1@Wq precomputed into d_ws by prep kernel.
// R4 fix: zero-init the H slab (K-pad octets 2,3 were uninitialized -> NaN*0=NaN).

typedef __attribute__((ext_vector_type(8))) short bf16x8;   // 8 bf16 = 4 VGPRs
typedef __attribute__((ext_vector_type(4))) float f32x4;

#define OFF_NF    0        // 16 tiles * 2176 (8 slabs * 272)
#define OFF_WPJ   34816    // 8 slabs * 1040
#define OFF_WA1Q  43136    // 8 slabs * 272
#define OFF_CF    45312    // 8 slabs * 272
#define OFF_ATTN  47488    // 8 slabs * 272
#define OFF_CFR   49664    // 16 * 68 * 4
#define OFF_HAQ   54016    // 16 * 16 * 4
#define OFF_REL   55040    // 256 * 3 * 4
#define OFF_H     58112    // 4 waves * 1088
#define SMEM_SZ   62464

__device__ __forceinline__ uint32_t packt(float a, float b){   // exact for bf16-grid values
  return (__float_as_uint(b) & 0xffff0000u) | (__float_as_uint(a) >> 16);
}
__device__ __forceinline__ uint32_t rne1(float a){
  uint32_t u = __float_as_uint(a);
  return (u + 0x7fffu + ((u >> 16) & 1u)) >> 16;
}
__device__ __forceinline__ uint32_t packr(float a, float b){ return rne1(a) | (rne1(b) << 16); }
__device__ __forceinline__ float blo(uint32_t u){ return __uint_as_float(u << 16); }
__device__ __forceinline__ float bhi(uint32_t u){ return __uint_as_float(u & 0xffff0000u); }

union FragU { uint32_t u[4]; bf16x8 f; };
__device__ __forceinline__ bf16x8 mkfrag(uint32_t a, uint32_t b, uint32_t c, uint32_t d){
  FragU x; x.u[0]=a; x.u[1]=b; x.u[2]=c; x.u[3]=d; return x.f;
}
__device__ __forceinline__ f32x4 MFMA(bf16x8 a, bf16x8 b, f32x4 c){
  return __builtin_amdgcn_mfma_f32_16x16x32_bf16(a, b, c, 0, 0, 0);
}

// ---------------- prep: fused weights into ws ----------------
// ws[0:1024)    Wa1k  = Wa1 @ Wk     (16x64)
// ws[1024:2048) Wa1p2 = Wa1 @ Wpe2   (16x64)
// ws[2048:3072) Wa1q  = Wa1 @ Wq     (16x64)
__global__ __launch_bounds__(256) void pt_prep(const float* __restrict__ Wq,
                                               const float* __restrict__ Wk,
                                               const float* __restrict__ Wpe2,
                                               const float* __restrict__ Wa1,
                                               float* __restrict__ ws){
  __shared__ float sa1[1024];
  const int tid = threadIdx.x;
  for (int i = tid; i < 1024; i += 256) sa1[i] = Wa1[i];
  __syncthreads();
  for (int e = tid; e < 3072; e += 256) {
    int mat = e >> 10, idx = e & 1023, m = idx >> 6, c = idx & 63;
    const float* W = (mat == 0) ? Wk : ((mat == 1) ? Wpe2 : Wq);
    float acc = 0.f;
    for (int o = 0; o < 64; o++) acc += sa1[m * 64 + o] * W[o * 64 + c];
    ws[e] = acc;
  }
}

// ---------------- main ----------------
__global__ __launch_bounds__(256) void pt_main(
    const float* __restrict__ cxyz,  const float* __restrict__ cfeat,
    const float* __restrict__ nxyz,  const float* __restrict__ nfeat,
    const float* __restrict__ Wpe1,  const float* __restrict__ Wv,
    const float* __restrict__ Wpe2,  const float* __restrict__ Wa2,
    const float* __restrict__ Wproj, const float* __restrict__ lnw,
    const float* __restrict__ lnb,   const float* __restrict__ ws,
    float* __restrict__ out)
{
  __shared__ char smem[SMEM_SZ] __attribute__((aligned(16)));
  const int tid  = threadIdx.x;
  const int wave = tid >> 6;
  const int lane = tid & 63;
  const int q    = lane >> 4;     // quad
  const int ll   = lane & 15;
  const int blk  = blockIdx.x;

  float* s_cfr = (float*)(smem + OFF_CFR);
  float* s_haq = (float*)(smem + OFF_HAQ);
  float* s_rel = (float*)(smem + OFF_REL);

  // ---------- staging ----------
  // zero the whole H region: octets 2,3 of each wave slab are the K-pad of the
  // logits A-operand and are never written later — must be 0, not garbage.
  {
    const uint4 z = {0u, 0u, 0u, 0u};
    for (int i = tid; i < 272; i += 256)
      *(uint4*)(smem + OFF_H + i * 16) = z;
  }
  // neigh_feat -> bf16 A-frag slabs (8 octet-tasks per row)
  {
    const float* nf_base = nfeat + (size_t)blk * (256 * 64);
#pragma unroll
    for (int it = 0; it < 8; it++) {
      int g = it * 256 + tid;
      int row = g >> 3, oct = g & 7;
      const float* src = nf_base + row * 64 + oct * 8;
      float4 a = *(const float4*)src;
      float4 b = *(const float4*)(src + 4);
      uint4 w;
      w.x = packt(a.x, a.y); w.y = packt(a.z, a.w);
      w.z = packt(b.x, b.y); w.w = packt(b.z, b.w);
      *(uint4*)(smem + OFF_NF + (row >> 4) * 2176 + oct * 272 + (row & 15) * 16) = w;
    }
  }
  // cfeat A-frags (tid<128) and Wa1q B-frags (tid>=128)
  {
    int task = tid & 127;
    int row = task >> 3, oct = task & 7;
    if (tid < 128) {
      const float* src = cfeat + ((size_t)(blk * 16) + row) * 64 + oct * 8;
      float4 a = *(const float4*)src;
      float4 b = *(const float4*)(src + 4);
      uint4 w;
      w.x = packt(a.x, a.y); w.y = packt(a.z, a.w);
      w.z = packt(b.x, b.y); w.w = packt(b.z, b.w);
      *(uint4*)(smem + OFF_CF + oct * 272 + row * 16) = w;
    } else {
      const float* src = ws + 2048 + row * 64 + oct * 8;   // Wa1q (computed -> RNE)
      float4 a = *(const float4*)src;
      float4 b = *(const float4*)(src + 4);
      uint4 w;
      w.x = packr(a.x, a.y); w.y = packr(a.z, a.w);
      w.z = packr(b.x, b.y); w.w = packr(b.z, b.w);
      *(uint4*)(smem + OFF_WA1Q + oct * 272 + row * 16) = w;
    }
  }
  // cfeat fp32 copy (residual), padded rows of 68
  {
    int row = tid >> 4, c4 = (tid & 15) * 4;
    float4 v = *(const float4*)(cfeat + ((size_t)(blk * 16) + row) * 64 + c4);
    *(float4*)(s_cfr + row * 68 + c4) = v;
  }
  // rel = nxyz - cxyz (fp32)
  {
    int row = tid;
#pragma unroll
    for (int d = 0; d < 3; d++) {
      float nx = nxyz[((size_t)(blk * 256) + row) * 3 + d];
      float cx = cxyz[((size_t)(blk * 16) + (row >> 4)) * 3 + d];
      s_rel[row * 3 + d] = nx - cx;
    }
  }
  // Wproj B-frags
#pragma unroll
  for (int it = 0; it < 2; it++) {
    int g = it * 256 + tid;
    int n = g >> 3, oct = g & 7;
    const float* src = Wproj + n * 64 + oct * 8;
    float4 a = *(const float4*)src;
    float4 b = *(const float4*)(src + 4);
    uint4 w;
    w.x = packt(a.x, a.y); w.y = packt(a.z, a.w);
    w.z = packt(b.x, b.y); w.w = packt(b.z, b.w);
    *(uint4*)(smem + OFF_WPJ + oct * 1040 + n * 16) = w;
  }

  // ---------- resident B-frags (VGPRs) ----------
  bf16x8 wvf[4][2], wp2f[4][2], wa2f[4], wa1kf[2], wa1pf[2];
#pragma unroll
  for (int nt = 0; nt < 4; nt++) {
#pragma unroll
    for (int s = 0; s < 2; s++) {
      const float* p1 = Wv   + (16 * nt + ll) * 64 + 32 * s + 8 * q;
      const float* p2 = Wpe2 + (16 * nt + ll) * 64 + 32 * s + 8 * q;
      float4 a = *(const float4*)p1, b = *(const float4*)(p1 + 4);
      wvf[nt][s]  = mkfrag(packt(a.x,a.y), packt(a.z,a.w), packt(b.x,b.y), packt(b.z,b.w));
      a = *(const float4*)p2; b = *(const float4*)(p2 + 4);
      wp2f[nt][s] = mkfrag(packt(a.x,a.y), packt(a.z,a.w), packt(b.x,b.y), packt(b.z,b.w));
    }
    if (q < 2) {
      const float* p3 = Wa2 + (16 * nt + ll) * 16 + 8 * q;
      float4 a = *(const float4*)p3, b = *(const float4*)(p3 + 4);
      wa2f[nt] = mkfrag(packt(a.x,a.y), packt(a.z,a.w), packt(b.x,b.y), packt(b.z,b.w));
    } else {
      wa2f[nt] = mkfrag(0u, 0u, 0u, 0u);   // k=16..31 zero-pad
    }
  }
#pragma unroll
  for (int s = 0; s < 2; s++) {
    const float* p1 = ws        + ll * 64 + 32 * s + 8 * q;   // Wa1k (computed -> RNE)
    const float* p2 = ws + 1024 + ll * 64 + 32 * s + 8 * q;   // Wa1pe2
    float4 a = *(const float4*)p1, b = *(const float4*)(p1 + 4);
    wa1kf[s] = mkfrag(packr(a.x,a.y), packr(a.z,a.w), packr(b.x,b.y), packr(b.z,b.w));
    a = *(const float4*)p2; b = *(const float4*)(p2 + 4);
    wa1pf[s] = mkfrag(packr(a.x,a.y), packr(a.z,a.w), packr(b.x,b.y), packr(b.z,b.w));
  }
  // Wpe1 rows this lane needs (k = 8q+j and 32+8q+j), packed bf16 (exact grid)
  uint32_t pe1xy[16], pe1z[8];
  {
    float zt[16];
#pragma unroll
    for (int i = 0; i < 16; i++) {
      int k = (i < 8) ? (8 * q + i) : (32 + 8 * q + (i - 8));
      pe1xy[i] = packt(Wpe1[k * 3 + 0], Wpe1[k * 3 + 1]);
      zt[i] = Wpe1[k * 3 + 2];
    }
#pragma unroll
    for (int i = 0; i < 8; i++) pe1z[i] = packt(zt[2 * i], zt[2 * i + 1]);
  }
  float lnw_r[4], lnb_r[4];
#pragma unroll
  for (int nt = 0; nt < 4; nt++) { lnw_r[nt] = lnw[16 * nt + ll]; lnb_r[nt] = lnb[16 * nt + ll]; }

  __syncthreads();

  // ---------- haq = CF @ (Wa1 Wq)^T  (16 pts x 16 mid), redundant per wave ----------
  {
    bf16x8 cf0 = *(const bf16x8*)(smem + OFF_CF + (0 + q) * 272 + ll * 16);
    bf16x8 cf1 = *(const bf16x8*)(smem + OFF_CF + (4 + q) * 272 + ll * 16);
    bf16x8 b0  = *(const bf16x8*)(smem + OFF_WA1Q + (0 + q) * 272 + ll * 16);
    bf16x8 b1  = *(const bf16x8*)(smem + OFF_WA1Q + (4 + q) * 272 + ll * 16);
    f32x4 acc = {0.f, 0.f, 0.f, 0.f};
    acc = MFMA(cf0, b0, acc);
    acc = MFMA(cf1, b1, acc);
    int p = 4 * q + wave;                 // dedup: wave writes reg r=wave
    s_haq[p * 16 + ll] = acc[wave];
  }
  __syncthreads();

  // ---------- per-point loop (wave handles points 4*wave .. 4*wave+3) ----------
  const f32x4 zero4 = {0.f, 0.f, 0.f, 0.f};
#pragma unroll 1
  for (int pi = 0; pi < 4; pi++) {
    const int t = 4 * wave + pi;

    bf16x8 nf0 = *(const bf16x8*)(smem + OFF_NF + t * 2176 + (0 + q) * 272 + ll * 16);
    bf16x8 nf1 = *(const bf16x8*)(smem + OFF_NF + t * 2176 + (4 + q) * 272 + ll * 16);

    const float r0 = s_rel[(t * 16 + ll) * 3 + 0];
    const float r1 = s_rel[(t * 16 + ll) * 3 + 1];
    const float r2 = s_rel[(t * 16 + ll) * 3 + 2];

    // T = relu(rel @ Wpe1^T) directly in A-frag layout
    uint32_t tf[8];
#pragma unroll
    for (int i2 = 0; i2 < 8; i2++) {
      float ta = fmaxf(blo(pe1xy[2*i2  ]) * r0 + bhi(pe1xy[2*i2  ]) * r1 + blo(pe1z[i2]) * r2, 0.f);
      float tb = fmaxf(blo(pe1xy[2*i2+1]) * r0 + bhi(pe1xy[2*i2+1]) * r1 + bhi(pe1z[i2]) * r2, 0.f);
      tf[i2] = packr(ta, tb);
    }
    bf16x8 t0 = mkfrag(tf[0], tf[1], tf[2], tf[3]);
    bf16x8 t1 = mkfrag(tf[4], tf[5], tf[6], tf[7]);

    f32x4 aV[4], aPE[4];
#pragma unroll
    for (int nt = 0; nt < 4; nt++) {
      aV[nt]  = MFMA(nf0, wvf[nt][0], zero4);  aV[nt]  = MFMA(nf1, wvf[nt][1], aV[nt]);
      aPE[nt] = MFMA(t0,  wp2f[nt][0], zero4); aPE[nt] = MFMA(t1,  wp2f[nt][1], aPE[nt]);
    }
    f32x4 aHK  = MFMA(nf0, wa1kf[0], zero4);  aHK  = MFMA(nf1, wa1kf[1], aHK);
    f32x4 aHPE = MFMA(t0,  wa1pf[0], zero4);  aHPE = MFMA(t1,  wa1pf[1], aHPE);

    // h = relu(haq - HK + HPE), C-layout -> LDS (A-frag layout) -> logits GEMM
    const float haqv = s_haq[t * 16 + ll];
#pragma unroll
    for (int r = 0; r < 4; r++) {
      float hv = fmaxf(haqv - aHK[r] + aHPE[r], 0.f);
      *(uint16_t*)(smem + OFF_H + wave * 1088 + (ll >> 3) * 272 + (4 * q + r) * 16 + (ll & 7) * 2)
          = (uint16_t)rne1(hv);
    }
    bf16x8 ha = *(const bf16x8*)(smem + OFF_H + wave * 1088 + q * 272 + ll * 16);

    f32x4 aW[4];
#pragma unroll
    for (int nt = 0; nt < 4; nt++) aW[nt] = MFMA(ha, wa2f[nt], zero4);

    // softmax over the 16 rows (neighbors) per column + combine with (V+PE)
    float outv[4];
#pragma unroll
    for (int nt = 0; nt < 4; nt++) {
      float mx = fmaxf(fmaxf(aW[nt][0], aW[nt][1]), fmaxf(aW[nt][2], aW[nt][3]));
      mx = fmaxf(mx, __shfl_xor(mx, 16, 64));
      mx = fmaxf(mx, __shfl_xor(mx, 32, 64));
      float den = 0.f, num = 0.f;
#pragma unroll
      for (int r = 0; r < 4; r++) {
        float e = __expf(aW[nt][r] - mx);
        den += e;
        num += e * (aV[nt][r] + aPE[nt][r]);
      }
      den += __shfl_xor(den, 16, 64); den += __shfl_xor(den, 32, 64);
      num += __shfl_xor(num, 16, 64); num += __shfl_xor(num, 32, 64);
      outv[nt] = num / den;
    }

    // write attn (bf16) into A-frag layout; this lane stores channel 16*q + ll
    *(uint16_t*)(smem + OFF_ATTN + (2 * q + (ll >> 3)) * 272 + t * 16 + (ll & 7) * 2)
        = (uint16_t)rne1(outv[q]);
  }
  __syncthreads();

  // ---------- proj + residual + layernorm ----------
  {
    bf16x8 at0 = *(const bf16x8*)(smem + OFF_ATTN + (0 + q) * 272 + ll * 16);
    bf16x8 at1 = *(const bf16x8*)(smem + OFF_ATTN + (4 + q) * 272 + ll * 16);
    f32x4 accP[4];
#pragma unroll
    for (int nt = 0; nt < 4; nt++) {
      bf16x8 w0 = *(const bf16x8*)(smem + OFF_WPJ + (0 + q) * 1040 + (16 * nt + ll) * 16);
      bf16x8 w1 = *(const bf16x8*)(smem + OFF_WPJ + (4 + q) * 1040 + (16 * nt + ll) * 16);
      accP[nt] = MFMA(at0, w0, zero4);
      accP[nt] = MFMA(at1, w1, accP[nt]);
    }
    const int p = 4 * q + wave;           // wave finalizes reg r=wave of each quad
    float x[4]; float ssum = 0.f;
#pragma unroll
    for (int nt = 0; nt < 4; nt++) {
      x[nt] = accP[nt][wave] + s_cfr[p * 68 + 16 * nt + ll];
      ssum += x[nt];
    }
    ssum += __shfl_xor(ssum, 1, 64); ssum += __shfl_xor(ssum, 2, 64);
    ssum += __shfl_xor(ssum, 4, 64); ssum += __shfl_xor(ssum, 8, 64);
    const float mu = ssum * (1.f / 64.f);
    float vsum = 0.f;
#pragma unroll
    for (int nt = 0; nt < 4; nt++) { float d = x[nt] - mu; vsum += d * d; }
    vsum += __shfl_xor(vsum, 1, 64); vsum += __shfl_xor(vsum, 2, 64);
    vsum += __shfl_xor(vsum, 4, 64); vsum += __shfl_xor(vsum, 8, 64);
    const float rs = rsqrtf(vsum * (1.f / 64.f) + 1e-5f);
    const size_t n = (size_t)blk * 16 + p;
#pragma unroll
    for (int nt = 0; nt < 4; nt++)
      out[n * 64 + 16 * nt + ll] = (x[nt] - mu) * rs * lnw_r[nt] + lnb_r[nt];
  }
}

extern "C" void kernel_launch(void* const* d_in, const int* in_sizes, int n_in,
                              void* d_out, int out_size, void* d_ws, size_t ws_size,
                              hipStream_t stream) {
  const float* cxyz  = (const float*)d_in[0];
  const float* cfeat = (const float*)d_in[1];
  const float* nxyz  = (const float*)d_in[2];
  const float* nfeat = (const float*)d_in[3];
  const float* Wq    = (const float*)d_in[4];
  const float* Wk    = (const float*)d_in[5];
  const float* Wv    = (const float*)d_in[6];
  const float* Wpe1  = (const float*)d_in[7];
  const float* Wpe2  = (const float*)d_in[8];
  const float* Wa1   = (const float*)d_in[9];
  const float* Wa2   = (const float*)d_in[10];
  const float* Wproj = (const float*)d_in[11];
  const float* lnw   = (const float*)d_in[12];
  const float* lnb   = (const float*)d_in[13];
  float* ws = (float*)d_ws;

  pt_prep<<<1, 256, 0, stream>>>(Wq, Wk, Wpe2, Wa1, ws);

  const int npts = in_sizes[1] / 64;   // B*S
  const int nblk = npts / 16;
  pt_main<<<nblk, 256, 0, stream>>>(cxyz, cfeat, nxyz, nfeat, Wpe1, Wv, Wpe2, Wa2,
                                    Wproj, lnw, lnb, ws, (float*)d_out);
}